// Round 2
// baseline (496.914 us; speedup 1.0000x reference)
//
#include <hip/hip_runtime.h>
#include <hip/hip_bf16.h>

typedef __hip_bfloat16 bf16;
typedef __attribute__((ext_vector_type(8))) __bf16 bf16x8;
typedef __attribute__((ext_vector_type(4))) float f32x4;

__device__ __forceinline__ void gld_lds16(const bf16* g, bf16* l) {
  __builtin_amdgcn_global_load_lds((const __attribute__((address_space(1))) void*)g,
                                   (__attribute__((address_space(3))) void*)l, 16, 0, 0);
}

// ---------------- weight prep: fp32 -> bf16, transposed layouts ----------------
__global__ __launch_bounds__(256) void prep_weights(
    const float* __restrict__ wq, const float* __restrict__ wk, const float* __restrict__ wv,
    const float* __restrict__ wo, const float* __restrict__ w1, const float* __restrict__ w2,
    bf16* __restrict__ WqkvT, bf16* __restrict__ woT, bf16* __restrict__ w1T, bf16* __restrict__ w2T)
{
  int i = blockIdx.x * 256 + threadIdx.x;
  if (i < 331776) {                 // WqkvT[n][d], n: 0..575 q, 576..1151 k, 1152..1727 v
    int n = i / 192, d = i % 192;
    int sel = n / 576, c = n % 576, h = c / 192, kd = c % 192;
    const float* w = (sel == 0) ? wq : (sel == 1 ? wk : wv);
    WqkvT[i] = __float2bfloat16(w[(d*3 + h)*192 + kd]);   // w[D][H][KD]
    return;
  }
  i -= 331776;
  if (i < 110592) {                 // woT[d][hk] = wo[hk][d], wo is [H*KD][D]
    int d = i / 576, hk = i % 576;
    woT[i] = __float2bfloat16(wo[hk*192 + d]);
    return;
  }
  i -= 110592;
  if (i < 147456) {                 // w1T[j][d] = w1[d][j], w1 is [192][768]
    int j = i / 192, d = i % 192;
    w1T[i] = __float2bfloat16(w1[d*768 + j]);
    return;
  }
  i -= 147456;
  if (i < 147456) {                 // w2T[d][j] = w2[j][d], w2 is [768][192]
    int d = i / 768, j = i % 768;
    w2T[i] = __float2bfloat16(w2[j*192 + d]);
  }
}

// ---------------- LayerNorm (D=192): 1 wave per row, 4 rows/block ----------------
__global__ __launch_bounds__(256) void ln_k(const float* __restrict__ x,
    const float* __restrict__ gamma, const float* __restrict__ beta,
    bf16* __restrict__ out)
{
  int row = blockIdx.x * 4 + (threadIdx.x >> 6);
  int lane = threadIdx.x & 63;
  const float* xr = x + (size_t)row * 192;
  float v0 = xr[lane], v1 = xr[lane + 64], v2 = xr[lane + 128];
  float s = v0 + v1 + v2;
  #pragma unroll
  for (int o = 32; o; o >>= 1) s += __shfl_xor(s, o);
  float mu = s * (1.f / 192.f);
  float d0 = v0 - mu, d1 = v1 - mu, d2 = v2 - mu;
  float q = d0*d0 + d1*d1 + d2*d2;
  #pragma unroll
  for (int o = 32; o; o >>= 1) q += __shfl_xor(q, o);
  float rs = rsqrtf(q * (1.f / 192.f) + 1e-3f);
  bf16* orow = out + (size_t)row * 192;
  orow[lane]       = __float2bfloat16(d0*rs*gamma[lane]       + beta[lane]);
  orow[lane + 64]  = __float2bfloat16(d1*rs*gamma[lane + 64]  + beta[lane + 64]);
  orow[lane + 128] = __float2bfloat16(d2*rs*gamma[lane + 128] + beta[lane + 128]);
}

// ---------------- generic GEMM C = A[M,K] * BT[N,K]^T, 128x64 tile, 4 waves ----------------
enum { EPI_QKV = 0, EPI_RES = 2, EPI_GELU = 3, EPI_OUT = 4 };

template<int EPI>
__global__ __launch_bounds__(256) void gemm_bt(
    const bf16* __restrict__ Aall, const bf16* __restrict__ BTall,
    int M, int N, int K,
    float* __restrict__ outF, bf16* __restrict__ outB,
    const float* __restrict__ bias, const float* __restrict__ resF,
    bf16* __restrict__ q_out, bf16* __restrict__ k_out, bf16* __restrict__ vT_out)
{
  const int tid = threadIdx.x, lane = tid & 63, wid = tid >> 6;
  const int wm = wid >> 1, wn = wid & 1;
  const int row0 = blockIdx.y * 128, col0 = blockIdx.x * 64;
  const bf16* A = Aall;
  const bf16* BT = BTall;
  __shared__ __align__(16) bf16 As[2][128 * 32];
  __shared__ __align__(16) bf16 Bs[2][64 * 32];
  f32x4 acc[4][2] = {};
  const int NT = K >> 5;

#define STAGE(buf_, kt_) do { \
    const bf16* Ab_ = A + (size_t)row0 * K + (kt_) * 32; \
    int c0_ = tid, r0_ = c0_ >> 2, cc0_ = (c0_ & 3) << 3; \
    gld_lds16(Ab_ + (size_t)r0_ * K + cc0_, &As[buf_][c0_ * 8]); \
    int c1_ = tid + 256, r1_ = c1_ >> 2, cc1_ = (c1_ & 3) << 3; \
    gld_lds16(Ab_ + (size_t)r1_ * K + cc1_, &As[buf_][c1_ * 8]); \
    const bf16* Bb_ = BT + (size_t)col0 * K + (kt_) * 32; \
    gld_lds16(Bb_ + (size_t)(tid >> 2) * K + ((tid & 3) << 3), &Bs[buf_][tid * 8]); \
  } while (0)

  STAGE(0, 0);
  for (int kt = 0; kt < NT; ++kt) {
    __syncthreads();
    const int buf = kt & 1;
    if (kt + 1 < NT) STAGE(buf ^ 1, kt + 1);
    const int koff = (lane >> 4) * 8;
    bf16x8 af[4], bfr[2];
    #pragma unroll
    for (int m = 0; m < 4; ++m)
      af[m] = *(const bf16x8*)&As[buf][(wm*64 + m*16 + (lane & 15))*32 + koff];
    #pragma unroll
    for (int n = 0; n < 2; ++n)
      bfr[n] = *(const bf16x8*)&Bs[buf][(wn*32 + n*16 + (lane & 15))*32 + koff];
    #pragma unroll
    for (int m = 0; m < 4; ++m)
      #pragma unroll
      for (int n = 0; n < 2; ++n)
        acc[m][n] = __builtin_amdgcn_mfma_f32_16x16x32_bf16(af[m], bfr[n], acc[m][n], 0, 0, 0);
  }
#undef STAGE

  const int rbase = row0 + wm * 64;
  const int cbase = col0 + wn * 32;
  #pragma unroll
  for (int m = 0; m < 4; ++m) {
    #pragma unroll
    for (int n = 0; n < 2; ++n) {
      const int col = cbase + n*16 + (lane & 15);
      const int rtop = rbase + m*16 + ((lane >> 4) << 2);
      #pragma unroll
      for (int j = 0; j < 4; ++j) {
        const int row = rtop + j;
        const float v = acc[m][n][j];
        if constexpr (EPI == EPI_QKV) {
          const int b = row >> 11, t = row & 2047;
          const int sel = col / 576, c2 = col % 576;
          const int h = c2 / 192, kd = c2 % 192;
          const bf16 bv = __float2bfloat16(v);
          const size_t hb_ = (size_t)(b * 3 + h);
          if (sel == 0)      q_out[(hb_ * 2048 + t) * 192 + kd] = bv;
          else if (sel == 1) k_out[(hb_ * 2048 + t) * 192 + kd] = bv;
          else               vT_out[(hb_ * 192 + kd) * 2048 + t] = bv;
        } else if constexpr (EPI == EPI_RES) {
          const size_t idx = (size_t)row * 192 + col;
          outF[idx] = resF[idx] + v;
        } else if constexpr (EPI == EPI_GELU) {
          const float u = v + bias[col];
          outB[(size_t)row * 768 + col] =
              __float2bfloat16(0.5f * u * (1.f + erff(u * 0.70710678118654752f)));
        } else if constexpr (EPI == EPI_OUT) {
          const size_t idx = (size_t)row * 192 + col;
          outF[idx] = outF[idx] + v + bias[col];
        }
      }
    }
  }
}

// ------- scores+exp: E = exp(pre-mixed QK^T / sqrt(192)), plus row partial sums -------
__global__ __launch_bounds__(256) void scores_exp_k(
    const bf16* __restrict__ q, const bf16* __restrict__ k,
    const float* __restrict__ pre_w, bf16* __restrict__ E,
    float* __restrict__ Lpart, int b0)
{
  const int tid = threadIdx.x, lane = tid & 63, wid = tid >> 6;
  const int wm = wid >> 1, wn = wid & 1;
  const int bx = blockIdx.x;
  const int s0 = bx * 64, t0 = blockIdx.y * 128;
  const int zb = blockIdx.z, b = b0 + zb;
  __shared__ __align__(16) bf16 Qs[2][128 * 32];
  __shared__ __align__(16) bf16 Ks[2][64 * 32];
  f32x4 acc[3][4][2] = {};

#define SSTAGE(buf_, h_, kt_) do { \
    const bf16* Qb_ = q + ((size_t)(b * 3 + (h_)) * 2048 + t0) * 192 + (kt_) * 32; \
    int c0_ = tid, r0_ = c0_ >> 2, cc0_ = (c0_ & 3) << 3; \
    gld_lds16(Qb_ + (size_t)r0_ * 192 + cc0_, &Qs[buf_][c0_ * 8]); \
    int c1_ = tid + 256, r1_ = c1_ >> 2, cc1_ = (c1_ & 3) << 3; \
    gld_lds16(Qb_ + (size_t)r1_ * 192 + cc1_, &Qs[buf_][c1_ * 8]); \
    const bf16* Kb_ = k + ((size_t)(b * 3 + (h_)) * 2048 + s0) * 192 + (kt_) * 32; \
    gld_lds16(Kb_ + (size_t)(tid >> 2) * 192 + ((tid & 3) << 3), &Ks[buf_][tid * 8]); \
  } while (0)

  SSTAGE(0, 0, 0);
  int step = 0;
  #pragma unroll
  for (int h = 0; h < 3; ++h) {
    #pragma unroll
    for (int kt = 0; kt < 6; ++kt, ++step) {
      __syncthreads();
      const int buf = step & 1;
      int nh = h, nkt = kt + 1;
      if (nkt == 6) { nkt = 0; ++nh; }
      if (nh < 3) SSTAGE(buf ^ 1, nh, nkt);
      const int koff = (lane >> 4) * 8;
      bf16x8 af[4], bfr[2];
      #pragma unroll
      for (int m = 0; m < 4; ++m)
        af[m] = *(const bf16x8*)&Qs[buf][(wm*64 + m*16 + (lane & 15))*32 + koff];
      #pragma unroll
      for (int n = 0; n < 2; ++n)
        bfr[n] = *(const bf16x8*)&Ks[buf][(wn*32 + n*16 + (lane & 15))*32 + koff];
      #pragma unroll
      for (int m = 0; m < 4; ++m)
        #pragma unroll
        for (int n = 0; n < 2; ++n)
          acc[h][m][n] = __builtin_amdgcn_mfma_f32_16x16x32_bf16(af[m], bfr[n], acc[h][m][n], 0, 0, 0);
    }
  }
#undef SSTAGE

  float pw[9];
  #pragma unroll
  for (int i = 0; i < 9; ++i) pw[i] = pre_w[i];
  const float rsq = 0.07216878364870323f;  // 1/sqrt(192)
  #pragma unroll
  for (int m = 0; m < 4; ++m) {
    #pragma unroll
    for (int j = 0; j < 4; ++j) {
      const int row = t0 + wm*64 + m*16 + ((lane >> 4) << 2) + j;
      float ev[2][3], sg[3] = {0.f, 0.f, 0.f};
      #pragma unroll
      for (int n = 0; n < 2; ++n)
        #pragma unroll
        for (int g = 0; g < 3; ++g) {
          const float v = (acc[0][m][n][j]*pw[g] + acc[1][m][n][j]*pw[3+g] + acc[2][m][n][j]*pw[6+g]) * rsq;
          const float e = __expf(v);
          ev[n][g] = e; sg[g] += e;
        }
      #pragma unroll
      for (int n = 0; n < 2; ++n)
        #pragma unroll
        for (int g = 0; g < 3; ++g)
          E[(((size_t)zb*3 + g) * 2048 + row) * 2048 + (s0 + wn*32 + n*16 + (lane & 15))] =
              __float2bfloat16(ev[n][g]);
      #pragma unroll
      for (int g = 0; g < 3; ++g) {
        #pragma unroll
        for (int o = 1; o < 16; o <<= 1) sg[g] += __shfl_xor(sg[g], o);
      }
      if ((lane & 15) == 0) {
        #pragma unroll
        for (int g = 0; g < 3; ++g)
          Lpart[(((size_t)zb*3 + g) * 2048 + row) * 64 + bx*2 + wn] = sg[g];
      }
    }
  }
}

// ---------------- rl = 1 / rowsum(Lpart) ----------------
__global__ __launch_bounds__(256) void reduce_l(const float* __restrict__ Lpart,
                                                float* __restrict__ rl)
{
  const int r = blockIdx.x * 4 + (threadIdx.x >> 6);
  const int lane = threadIdx.x & 63;
  float v = Lpart[(size_t)r * 64 + lane];
  #pragma unroll
  for (int o = 32; o; o >>= 1) v += __shfl_xor(v, o);
  if (lane == 0) rl[r] = 1.f / v;
}

// ------- fused post-mix + PV: ctx[t, g2*192+kd] = sum_s (sum_g pw[g,g2]*rl[g,t]*E_g[t,s]) * V[s,g2,kd]
__global__ __launch_bounds__(256, 2) void mixpv_k(
    const bf16* __restrict__ E, const bf16* __restrict__ vT,
    const float* __restrict__ rl, const float* __restrict__ post_w,
    bf16* __restrict__ ctx, int b0)
{
  const int tid = threadIdx.x, lane = tid & 63, w = tid >> 6;
  const int t0 = blockIdx.x * 32;
  const int zb = blockIdx.y, b = b0 + zb;
  // LDS: bytes [0,6144): E tiles, 3 planes of [32 rows][64B]; [6144,43008): V tiles, 3 planes of [192][64B]
  __shared__ __align__(16) bf16 smem[21504];
  f32x4 acc[3][2][3] = {};

  float pw[9];
  #pragma unroll
  for (int i = 0; i < 9; ++i) pw[i] = post_w[i];
  float rlv[3][2];
  #pragma unroll
  for (int g = 0; g < 3; ++g)
    #pragma unroll
    for (int m = 0; m < 2; ++m)
      rlv[g][m] = rl[(((size_t)zb*3 + g) << 11) + t0 + m*16 + (lane & 15)];

  for (int s0 = 0; s0 < 2048; s0 += 32) {
    __syncthreads();   // previous iteration's LDS reads complete
    // stage: 2688 16B lines (E: 384, V: 2304), source-swizzled (slot ^= (row>>1)&3)
    for (int seg = w; seg < 42; seg += 4) {
      const int line = seg * 64 + lane;
      const bf16* gsrc;
      if (line < 384) {
        const int g = line >> 7, rem = line & 127, row = rem >> 2, sp = rem & 3;
        const int sl = sp ^ ((row >> 1) & 3);
        gsrc = E + (((size_t)(zb*3 + g) * 2048) + t0 + row) * 2048 + s0 + sl*8;
      } else {
        const int vl = line - 384;
        const int g = (unsigned)vl / 768u, rem = vl - g*768, row = rem >> 2, sp = rem & 3;
        const int sl = sp ^ ((row >> 1) & 3);
        gsrc = vT + (((size_t)(b*3 + g) * 192) + row) * 2048 + s0 + sl*8;
      }
      gld_lds16(gsrc, &smem[line * 8]);
    }
    __syncthreads();   // staged data visible (compiler drains vmcnt before barrier)

    // B fragments: V^T rows (kd), swizzled slot
    bf16x8 Bf[3][3];
    #pragma unroll
    for (int g2 = 0; g2 < 3; ++g2)
      #pragma unroll
      for (int n = 0; n < 3; ++n) {
        const int kd = w*48 + n*16 + (lane & 15);
        const int ph = (lane >> 4) ^ ((kd >> 1) & 3);
        Bf[g2][n] = *(const bf16x8*)&smem[(384 + g2*768 + kd*4 + ph) * 8];
      }
    #pragma unroll
    for (int m = 0; m < 2; ++m) {
      bf16x8 Ef[3];
      #pragma unroll
      for (int g = 0; g < 3; ++g) {
        const int row = m*16 + (lane & 15);
        const int ph = (lane >> 4) ^ ((row >> 1) & 3);
        Ef[g] = *(const bf16x8*)&smem[(g*128 + row*4 + ph) * 8];
      }
      // mix: p''[g2] = sum_g pw[g*3+g2] * (E_g * rl_g)
      float en[3][8];
      #pragma unroll
      for (int g = 0; g < 3; ++g)
        #pragma unroll
        for (int j = 0; j < 8; ++j)
          en[g][j] = (float)Ef[g][j] * rlv[g][m];
      bf16x8 pa[3];
      #pragma unroll
      for (int g2 = 0; g2 < 3; ++g2)
        #pragma unroll
        for (int j = 0; j < 8; ++j)
          pa[g2][j] = (__bf16)(en[0][j]*pw[g2] + en[1][j]*pw[3+g2] + en[2][j]*pw[6+g2]);
      #pragma unroll
      for (int g2 = 0; g2 < 3; ++g2)
        #pragma unroll
        for (int n = 0; n < 3; ++n)
          acc[g2][m][n] = __builtin_amdgcn_mfma_f32_16x16x32_bf16(pa[g2], Bf[g2][n], acc[g2][m][n], 0, 0, 0);
    }
  }

  #pragma unroll
  for (int g2 = 0; g2 < 3; ++g2)
    #pragma unroll
    for (int m = 0; m < 2; ++m)
      #pragma unroll
      for (int n = 0; n < 3; ++n) {
        const int col = w*48 + n*16 + (lane & 15);
        const int rtop = t0 + m*16 + ((lane >> 4) << 2);
        #pragma unroll
        for (int j = 0; j < 4; ++j)
          ctx[((size_t)b * 2048 + rtop + j) * 576 + g2*192 + col] =
              __float2bfloat16(acc[g2][m][n][j]);
      }
}

// ---------------- host launcher ----------------
extern "C" void kernel_launch(void* const* d_in, const int* in_sizes, int n_in,
                              void* d_out, int out_size, void* d_ws, size_t ws_size,
                              hipStream_t stream)
{
  (void)in_sizes; (void)n_in; (void)out_size;
  const float* x      = (const float*)d_in[0];
  const float* gamma1 = (const float*)d_in[1];
  const float* beta1  = (const float*)d_in[2];
  const float* gamma2 = (const float*)d_in[3];
  const float* beta2  = (const float*)d_in[4];
  const float* wq     = (const float*)d_in[5];
  const float* wk     = (const float*)d_in[6];
  const float* wv     = (const float*)d_in[7];
  const float* wo     = (const float*)d_in[8];
  const float* pre_w  = (const float*)d_in[9];
  const float* post_w = (const float*)d_in[10];
  const float* w1     = (const float*)d_in[11];
  const float* b1     = (const float*)d_in[12];
  const float* w2     = (const float*)d_in[13];
  const float* b2     = (const float*)d_in[14];
  float* out = (float*)d_out;

  uint8_t* base = (uint8_t*)d_ws;
  size_t off = 0;
  auto alloc = [&](size_t bytes) {
    uint8_t* r = base + off; off += (bytes + 255) & ~(size_t)255; return r;
  };
  bf16* nb    = (bf16*)alloc((size_t)16384 * 192 * 2);    // n1 / n2
  bf16* qb    = (bf16*)alloc((size_t)9437184 * 2);        // q [B,H,T,KD]
  bf16* kb    = (bf16*)alloc((size_t)9437184 * 2);        // k [B,H,T,KD]
  bf16* vTb   = (bf16*)alloc((size_t)9437184 * 2);        // vT [B,H,KD,T]
  bf16* ctxb  = (bf16*)alloc((size_t)16384 * 576 * 2);    // ctx [BT, H*KD]
  bf16* WqkvT = (bf16*)alloc((size_t)331776 * 2);
  bf16* woT   = (bf16*)alloc((size_t)110592 * 2);
  bf16* w1T   = (bf16*)alloc((size_t)147456 * 2);
  bf16* w2T   = (bf16*)alloc((size_t)147456 * 2);
  float* Lpart = (float*)alloc((size_t)8 * 3 * 2048 * 64 * 4);
  float* rlb   = (float*)alloc((size_t)8 * 3 * 2048 * 4);
  bf16* hb    = qb;  // overlay: q/k dead by MLP time (25.2MB fits in q+k 37.7MB)

  const size_t sbytes = (size_t)3 * 2048 * 2048 * 2;      // per-batch E slab (bf16)
  int chunk = 1;
  if (off + 8 * sbytes <= ws_size)      chunk = 8;
  else if (off + 4 * sbytes <= ws_size) chunk = 4;
  else if (off + 2 * sbytes <= ws_size) chunk = 2;
  bf16* Eslab = (bf16*)alloc((size_t)chunk * sbytes);

  prep_weights<<<2880, 256, 0, stream>>>(wq, wk, wv, wo, w1, w2, WqkvT, woT, w1T, w2T);
  ln_k<<<4096, 256, 0, stream>>>(x, gamma1, beta1, nb);
  gemm_bt<EPI_QKV><<<dim3(27, 128, 1), 256, 0, stream>>>(nb, WqkvT, 16384, 1728, 192,
      nullptr, nullptr, nullptr, nullptr, qb, kb, vTb);
  for (int b0 = 0; b0 < 8; b0 += chunk) {
    scores_exp_k<<<dim3(32, 16, chunk), 256, 0, stream>>>(qb, kb, pre_w, Eslab, Lpart, b0);
    reduce_l<<<chunk * 1536, 256, 0, stream>>>(Lpart, rlb);
    mixpv_k<<<dim3(64, chunk), 256, 0, stream>>>(Eslab, vTb, rlb, post_w, ctxb, b0);
  }
  gemm_bt<EPI_RES><<<dim3(3, 128, 1), 256, 0, stream>>>(ctxb, woT, 16384, 192, 576,
      out, nullptr, nullptr, x, nullptr, nullptr, nullptr);
  ln_k<<<4096, 256, 0, stream>>>(out, gamma2, beta2, nb);
  gemm_bt<EPI_GELU><<<dim3(12, 128, 1), 256, 0, stream>>>(nb, w1T, 16384, 768, 192,
      nullptr, hb, b1, nullptr, nullptr, nullptr, nullptr);
  gemm_bt<EPI_OUT><<<dim3(3, 128, 1), 256, 0, stream>>>(hb, w2T, 16384, 192, 768,
      out, nullptr, b2, nullptr, nullptr, nullptr, nullptr);
}

// Round 3
// 402.416 us; speedup vs baseline: 1.2348x; 1.2348x over previous
//
#include <hip/hip_runtime.h>
#include <hip/hip_bf16.h>

typedef __hip_bfloat16 bf16;
typedef __attribute__((ext_vector_type(8))) __bf16 bf16x8;
typedef __attribute__((ext_vector_type(4))) float f32x4;

__device__ __forceinline__ void gld_lds16(const bf16* g, bf16* l) {
  __builtin_amdgcn_global_load_lds((const __attribute__((address_space(1))) void*)g,
                                   (__attribute__((address_space(3))) void*)l, 16, 0, 0);
}

// ---------------- weight prep: fp32 -> bf16, transposed / premixed layouts ----------------
__global__ __launch_bounds__(256) void prep_weights(
    const float* __restrict__ wq, const float* __restrict__ wk, const float* __restrict__ wv,
    const float* __restrict__ wo, const float* __restrict__ post_w,
    const float* __restrict__ w1, const float* __restrict__ w2,
    bf16* __restrict__ WqkvT, bf16* __restrict__ W2postT,
    bf16* __restrict__ w1T, bf16* __restrict__ w2T)
{
  int i = blockIdx.x * 256 + threadIdx.x;
  if (i < 331776) {                 // WqkvT[n][d], n: 0..575 q, 576..1151 k, 1152..1727 v
    int n = i / 192, d = i % 192;
    int sel = n / 576, c = n % 576, h = c / 192, kd = c % 192;
    const float* w = (sel == 0) ? wq : (sel == 1 ? wk : wv);
    WqkvT[i] = __float2bfloat16(w[(d*3 + h)*192 + kd]);   // w[D][H][KD]
    return;
  }
  i -= 331776;
  if (i < 331776) {                 // W2postT[n=(h*192+d)][c=(g2*192+kd)] = post_w[h,g2]*wo[c][d]
    int n = i / 576, c = i % 576;
    int h = n / 192, d = n % 192, g2 = c / 192;
    W2postT[i] = __float2bfloat16(post_w[h*3 + g2] * wo[c*192 + d]);
    return;
  }
  i -= 331776;
  if (i < 147456) {                 // w1T[j][d] = w1[d][j], w1 is [192][768]
    int j = i / 192, d = i % 192;
    w1T[i] = __float2bfloat16(w1[d*768 + j]);
    return;
  }
  i -= 147456;
  if (i < 147456) {                 // w2T[d][j] = w2[j][d], w2 is [768][192]
    int d = i / 768, j = i % 768;
    w2T[i] = __float2bfloat16(w2[j*192 + d]);
  }
}

// ---------------- LayerNorm (D=192): 1 wave per row, 4 rows/block ----------------
__global__ __launch_bounds__(256) void ln_k(const float* __restrict__ x,
    const float* __restrict__ gamma, const float* __restrict__ beta,
    bf16* __restrict__ out)
{
  int row = blockIdx.x * 4 + (threadIdx.x >> 6);
  int lane = threadIdx.x & 63;
  const float* xr = x + (size_t)row * 192;
  float v0 = xr[lane], v1 = xr[lane + 64], v2 = xr[lane + 128];
  float s = v0 + v1 + v2;
  #pragma unroll
  for (int o = 32; o; o >>= 1) s += __shfl_xor(s, o);
  float mu = s * (1.f / 192.f);
  float d0 = v0 - mu, d1 = v1 - mu, d2 = v2 - mu;
  float q = d0*d0 + d1*d1 + d2*d2;
  #pragma unroll
  for (int o = 32; o; o >>= 1) q += __shfl_xor(q, o);
  float rs = rsqrtf(q * (1.f / 192.f) + 1e-3f);
  bf16* orow = out + (size_t)row * 192;
  orow[lane]       = __float2bfloat16(d0*rs*gamma[lane]       + beta[lane]);
  orow[lane + 64]  = __float2bfloat16(d1*rs*gamma[lane + 64]  + beta[lane + 64]);
  orow[lane + 128] = __float2bfloat16(d2*rs*gamma[lane + 128] + beta[lane + 128]);
}

// ---------------- generic GEMM C = A[M,K] * BT[N,K]^T, 128x64 tile, 4 waves ----------------
enum { EPI_QKV = 0, EPI_MT = 1, EPI_GELU = 3, EPI_OUT = 4 };

template<int EPI>
__global__ __launch_bounds__(256) void gemm_bt(
    const bf16* __restrict__ A, const bf16* __restrict__ BT,
    int M, int N, int K,
    float* __restrict__ outF, bf16* __restrict__ outB,
    const float* __restrict__ bias,
    bf16* __restrict__ q_out, bf16* __restrict__ k_out, bf16* __restrict__ v_out)
{
  const int tid = threadIdx.x, lane = tid & 63, wid = tid >> 6;
  const int wm = wid >> 1, wn = wid & 1;
  const int row0 = blockIdx.y * 128, col0 = blockIdx.x * 64;
  __shared__ __align__(16) bf16 As[2][128 * 32];
  __shared__ __align__(16) bf16 Bs[2][64 * 32];
  f32x4 acc[4][2] = {};
  const int NT = K >> 5;

#define STAGE(buf_, kt_) do { \
    const bf16* Ab_ = A + (size_t)row0 * K + (kt_) * 32; \
    int c0_ = tid, r0_ = c0_ >> 2, cc0_ = (c0_ & 3) << 3; \
    gld_lds16(Ab_ + (size_t)r0_ * K + cc0_, &As[buf_][c0_ * 8]); \
    int c1_ = tid + 256, r1_ = c1_ >> 2, cc1_ = (c1_ & 3) << 3; \
    gld_lds16(Ab_ + (size_t)r1_ * K + cc1_, &As[buf_][c1_ * 8]); \
    const bf16* Bb_ = BT + (size_t)col0 * K + (kt_) * 32; \
    gld_lds16(Bb_ + (size_t)(tid >> 2) * K + ((tid & 3) << 3), &Bs[buf_][tid * 8]); \
  } while (0)

  STAGE(0, 0);
  for (int kt = 0; kt < NT; ++kt) {
    __syncthreads();
    const int buf = kt & 1;
    if (kt + 1 < NT) STAGE(buf ^ 1, kt + 1);
    const int koff = (lane >> 4) * 8;
    bf16x8 af[4], bfr[2];
    #pragma unroll
    for (int m = 0; m < 4; ++m)
      af[m] = *(const bf16x8*)&As[buf][(wm*64 + m*16 + (lane & 15))*32 + koff];
    #pragma unroll
    for (int n = 0; n < 2; ++n)
      bfr[n] = *(const bf16x8*)&Bs[buf][(wn*32 + n*16 + (lane & 15))*32 + koff];
    #pragma unroll
    for (int m = 0; m < 4; ++m)
      #pragma unroll
      for (int n = 0; n < 2; ++n)
        acc[m][n] = __builtin_amdgcn_mfma_f32_16x16x32_bf16(af[m], bfr[n], acc[m][n], 0, 0, 0);
  }
#undef STAGE

  const int rbase = row0 + wm * 64;
  const int cbase = col0 + wn * 32;
  #pragma unroll
  for (int m = 0; m < 4; ++m) {
    #pragma unroll
    for (int n = 0; n < 2; ++n) {
      const int col = cbase + n*16 + (lane & 15);
      const int rtop = rbase + m*16 + ((lane >> 4) << 2);
      #pragma unroll
      for (int j = 0; j < 4; ++j) {
        const int row = rtop + j;
        const float v = acc[m][n][j];
        if constexpr (EPI == EPI_QKV) {
          const int b = row >> 11, t = row & 2047;
          const int sel = col / 576, c2 = col % 576;
          const bf16 bv = __float2bfloat16(v);
          if (sel == 2) {
            v_out[(size_t)row * 576 + c2] = bv;      // v row-major [b,t,(h,kd)]
          } else {
            const int h = c2 / 192, kd = c2 % 192;
            const size_t hb_ = (size_t)(b * 3 + h);
            if (sel == 0) q_out[(hb_ * 2048 + t) * 192 + kd] = bv;
            else          k_out[(hb_ * 2048 + t) * 192 + kd] = bv;
          }
        } else if constexpr (EPI == EPI_MT) {
          // MT[b][(h*192+d)=col][s=t]
          outB[((size_t)((row >> 11) * 576 + col)) * 2048 + (row & 2047)] = __float2bfloat16(v);
        } else if constexpr (EPI == EPI_GELU) {
          const float u = v + bias[col];
          outB[(size_t)row * 768 + col] =
              __float2bfloat16(0.5f * u * (1.f + erff(u * 0.70710678118654752f)));
        } else if constexpr (EPI == EPI_OUT) {
          const size_t idx = (size_t)row * 192 + col;
          outF[idx] = outF[idx] + v + bias[col];
        }
      }
    }
  }
}

// ------- scores+exp: E = exp(pre-mixed QK^T / sqrt(192)), plus row partial sums -------
__global__ __launch_bounds__(256) void scores_exp_k(
    const bf16* __restrict__ q, const bf16* __restrict__ k,
    const float* __restrict__ pre_w, bf16* __restrict__ E,
    float* __restrict__ Lpart, int b0)
{
  const int tid = threadIdx.x, lane = tid & 63, wid = tid >> 6;
  const int wm = wid >> 1, wn = wid & 1;
  const int bx = blockIdx.x;
  const int s0 = bx * 64, t0 = blockIdx.y * 128;
  const int zb = blockIdx.z, b = b0 + zb;
  __shared__ __align__(16) bf16 Qs[2][128 * 32];
  __shared__ __align__(16) bf16 Ks[2][64 * 32];
  f32x4 acc[3][4][2] = {};

#define SSTAGE(buf_, h_, kt_) do { \
    const bf16* Qb_ = q + ((size_t)(b * 3 + (h_)) * 2048 + t0) * 192 + (kt_) * 32; \
    int c0_ = tid, r0_ = c0_ >> 2, cc0_ = (c0_ & 3) << 3; \
    gld_lds16(Qb_ + (size_t)r0_ * 192 + cc0_, &Qs[buf_][c0_ * 8]); \
    int c1_ = tid + 256, r1_ = c1_ >> 2, cc1_ = (c1_ & 3) << 3; \
    gld_lds16(Qb_ + (size_t)r1_ * 192 + cc1_, &Qs[buf_][c1_ * 8]); \
    const bf16* Kb_ = k + ((size_t)(b * 3 + (h_)) * 2048 + s0) * 192 + (kt_) * 32; \
    gld_lds16(Kb_ + (size_t)(tid >> 2) * 192 + ((tid & 3) << 3), &Ks[buf_][tid * 8]); \
  } while (0)

  SSTAGE(0, 0, 0);
  int step = 0;
  #pragma unroll
  for (int h = 0; h < 3; ++h) {
    #pragma unroll
    for (int kt = 0; kt < 6; ++kt, ++step) {
      __syncthreads();
      const int buf = step & 1;
      int nh = h, nkt = kt + 1;
      if (nkt == 6) { nkt = 0; ++nh; }
      if (nh < 3) SSTAGE(buf ^ 1, nh, nkt);
      const int koff = (lane >> 4) * 8;
      bf16x8 af[4], bfr[2];
      #pragma unroll
      for (int m = 0; m < 4; ++m)
        af[m] = *(const bf16x8*)&Qs[buf][(wm*64 + m*16 + (lane & 15))*32 + koff];
      #pragma unroll
      for (int n = 0; n < 2; ++n)
        bfr[n] = *(const bf16x8*)&Ks[buf][(wn*32 + n*16 + (lane & 15))*32 + koff];
      #pragma unroll
      for (int m = 0; m < 4; ++m)
        #pragma unroll
        for (int n = 0; n < 2; ++n)
          acc[h][m][n] = __builtin_amdgcn_mfma_f32_16x16x32_bf16(af[m], bfr[n], acc[h][m][n], 0, 0, 0);
    }
  }
#undef SSTAGE

  float pw[9];
  #pragma unroll
  for (int i = 0; i < 9; ++i) pw[i] = pre_w[i];
  const float rsq = 0.07216878364870323f;  // 1/sqrt(192)
  #pragma unroll
  for (int m = 0; m < 4; ++m) {
    #pragma unroll
    for (int j = 0; j < 4; ++j) {
      const int row = t0 + wm*64 + m*16 + ((lane >> 4) << 2) + j;
      float ev[2][3], sg[3] = {0.f, 0.f, 0.f};
      #pragma unroll
      for (int n = 0; n < 2; ++n)
        #pragma unroll
        for (int g = 0; g < 3; ++g) {
          const float v = (acc[0][m][n][j]*pw[g] + acc[1][m][n][j]*pw[3+g] + acc[2][m][n][j]*pw[6+g]) * rsq;
          const float e = __expf(v);
          ev[n][g] = e; sg[g] += e;
        }
      #pragma unroll
      for (int n = 0; n < 2; ++n)
        #pragma unroll
        for (int g = 0; g < 3; ++g)
          E[(((size_t)zb*3 + g) * 2048 + row) * 2048 + (s0 + wn*32 + n*16 + (lane & 15))] =
              __float2bfloat16(ev[n][g]);
      #pragma unroll
      for (int g = 0; g < 3; ++g) {
        #pragma unroll
        for (int o = 1; o < 16; o <<= 1) sg[g] += __shfl_xor(sg[g], o);
      }
      if ((lane & 15) == 0) {
        #pragma unroll
        for (int g = 0; g < 3; ++g)
          Lpart[(((size_t)zb*3 + g) * 2048 + row) * 64 + bx*2 + wn] = sg[g];
      }
    }
  }
}

// ---------------- rl = 1 / rowsum(Lpart) ----------------
__global__ __launch_bounds__(256) void reduce_l(const float* __restrict__ Lpart,
                                                float* __restrict__ rl)
{
  const int r = blockIdx.x * 4 + (threadIdx.x >> 6);
  const int lane = threadIdx.x & 63;
  float v = Lpart[(size_t)r * 64 + lane];
  #pragma unroll
  for (int o = 32; o; o >>= 1) v += __shfl_xor(v, o);
  if (lane == 0) rl[r] = 1.f / v;
}

// ------- pvout: out[b,t,d] = x[b,t,d] + sum_h rl[h,t] * sum_s E_h[t,s] * MT[b][(h,d)][s] -------
// 3-plane GEMM, 64x64 tile, 4 waves (2x2), K=2048 over s.
__global__ __launch_bounds__(256) void pvout_k(
    const bf16* __restrict__ E, const bf16* __restrict__ MT,
    const float* __restrict__ rl, const float* __restrict__ x,
    float* __restrict__ out, int b0)
{
  const int tid = threadIdx.x, lane = tid & 63, wid = tid >> 6;
  const int wm = wid >> 1, wn = wid & 1;
  const int col0 = blockIdx.x * 64, row0 = blockIdx.y * 64;
  const int zb = blockIdx.z, b = b0 + zb;
  __shared__ __align__(16) bf16 Es[2][3][64 * 32];
  __shared__ __align__(16) bf16 Ms[2][3][64 * 32];
  f32x4 acc[3][2][2] = {};
  const int r_ = tid >> 2, c8_ = (tid & 3) << 3;

#define PSTAGE(buf_, kt_) do { \
    const int s0_ = (kt_) * 32; \
    _Pragma("unroll") \
    for (int g_ = 0; g_ < 3; ++g_) { \
      gld_lds16(E + ((size_t)(zb*3 + g_) * 2048 + row0 + r_) * 2048 + s0_ + c8_, \
                &Es[buf_][g_][tid * 8]); \
      gld_lds16(MT + ((size_t)(b*576 + g_*192 + col0 + r_)) * 2048 + s0_ + c8_, \
                &Ms[buf_][g_][tid * 8]); \
    } \
  } while (0)

  PSTAGE(0, 0);
  for (int kt = 0; kt < 64; ++kt) {
    __syncthreads();
    const int buf = kt & 1;
    if (kt + 1 < 64) PSTAGE(buf ^ 1, kt + 1);
    const int koff = (lane >> 4) * 8;
    bf16x8 af[3][2], bfr[3][2];
    #pragma unroll
    for (int g = 0; g < 3; ++g) {
      #pragma unroll
      for (int m = 0; m < 2; ++m)
        af[g][m] = *(const bf16x8*)&Es[buf][g][(wm*32 + m*16 + (lane & 15))*32 + koff];
      #pragma unroll
      for (int n = 0; n < 2; ++n)
        bfr[g][n] = *(const bf16x8*)&Ms[buf][g][(wn*32 + n*16 + (lane & 15))*32 + koff];
    }
    #pragma unroll
    for (int g = 0; g < 3; ++g)
      #pragma unroll
      for (int m = 0; m < 2; ++m)
        #pragma unroll
        for (int n = 0; n < 2; ++n)
          acc[g][m][n] = __builtin_amdgcn_mfma_f32_16x16x32_bf16(af[g][m], bfr[g][n], acc[g][m][n], 0, 0, 0);
  }
#undef PSTAGE

  #pragma unroll
  for (int m = 0; m < 2; ++m) {
    const int rtop = row0 + wm*32 + m*16 + ((lane >> 4) << 2);
    #pragma unroll
    for (int j = 0; j < 4; ++j) {
      const int row = rtop + j;
      float rlv[3];
      #pragma unroll
      for (int g = 0; g < 3; ++g) rlv[g] = rl[((size_t)(zb*3 + g) << 11) + row];
      #pragma unroll
      for (int n = 0; n < 2; ++n) {
        const int col = col0 + wn*32 + n*16 + (lane & 15);
        const size_t idx = ((size_t)b * 2048 + row) * 192 + col;
        out[idx] = x[idx] + rlv[0]*acc[0][m][n][j] + rlv[1]*acc[1][m][n][j] + rlv[2]*acc[2][m][n][j];
      }
    }
  }
}

// ---------------- host launcher ----------------
extern "C" void kernel_launch(void* const* d_in, const int* in_sizes, int n_in,
                              void* d_out, int out_size, void* d_ws, size_t ws_size,
                              hipStream_t stream)
{
  (void)in_sizes; (void)n_in; (void)out_size;
  const float* x      = (const float*)d_in[0];
  const float* gamma1 = (const float*)d_in[1];
  const float* beta1  = (const float*)d_in[2];
  const float* gamma2 = (const float*)d_in[3];
  const float* beta2  = (const float*)d_in[4];
  const float* wq     = (const float*)d_in[5];
  const float* wk     = (const float*)d_in[6];
  const float* wv     = (const float*)d_in[7];
  const float* wo     = (const float*)d_in[8];
  const float* pre_w  = (const float*)d_in[9];
  const float* post_w = (const float*)d_in[10];
  const float* w1     = (const float*)d_in[11];
  const float* b1     = (const float*)d_in[12];
  const float* w2     = (const float*)d_in[13];
  const float* b2     = (const float*)d_in[14];
  float* out = (float*)d_out;

  uint8_t* base = (uint8_t*)d_ws;
  size_t off = 0;
  auto alloc = [&](size_t bytes) {
    uint8_t* r = base + off; off += (bytes + 255) & ~(size_t)255; return r;
  };
  bf16* nb      = (bf16*)alloc((size_t)16384 * 192 * 2);    // n1 / n2
  bf16* qb      = (bf16*)alloc((size_t)9437184 * 2);        // q [B,H,T,KD]
  bf16* kb      = (bf16*)alloc((size_t)9437184 * 2);        // k [B,H,T,KD]
  bf16* vb      = (bf16*)alloc((size_t)16384 * 576 * 2);    // v [B,T,(H,KD)]
  bf16* MTslab  = (bf16*)alloc((size_t)8 * 576 * 2048 * 2); // MT [B][(h,d)][s]
  bf16* WqkvT   = (bf16*)alloc((size_t)331776 * 2);
  bf16* W2postT = (bf16*)alloc((size_t)331776 * 2);
  bf16* w1T     = (bf16*)alloc((size_t)147456 * 2);
  bf16* w2T     = (bf16*)alloc((size_t)147456 * 2);
  float* Lpart  = (float*)alloc((size_t)8 * 3 * 2048 * 64 * 4);
  float* rlb    = (float*)alloc((size_t)8 * 3 * 2048 * 4);
  bf16* hb      = qb;  // overlay: q/k dead by MLP time (25.2MB fits in q+k 37.7MB)

  const size_t sbytes = (size_t)3 * 2048 * 2048 * 2;        // per-batch E slab (bf16)
  int chunk = 1;
  if (off + 8 * sbytes <= ws_size)      chunk = 8;
  else if (off + 4 * sbytes <= ws_size) chunk = 4;
  else if (off + 2 * sbytes <= ws_size) chunk = 2;
  bf16* Eslab = (bf16*)alloc((size_t)chunk * sbytes);

  prep_weights<<<3744, 256, 0, stream>>>(wq, wk, wv, wo, post_w, w1, w2,
                                         WqkvT, W2postT, w1T, w2T);
  ln_k<<<4096, 256, 0, stream>>>(x, gamma1, beta1, nb);
  gemm_bt<EPI_QKV><<<dim3(27, 128, 1), 256, 0, stream>>>(nb, WqkvT, 16384, 1728, 192,
      nullptr, nullptr, nullptr, qb, kb, vb);
  gemm_bt<EPI_MT><<<dim3(9, 128, 1), 256, 0, stream>>>(vb, W2postT, 16384, 576, 576,
      nullptr, MTslab, nullptr, nullptr, nullptr, nullptr);
  for (int b0 = 0; b0 < 8; b0 += chunk) {
    scores_exp_k<<<dim3(32, 16, chunk), 256, 0, stream>>>(qb, kb, pre_w, Eslab, Lpart, b0);
    reduce_l<<<chunk * 1536, 256, 0, stream>>>(Lpart, rlb);
    pvout_k<<<dim3(3, 32, chunk), 256, 0, stream>>>(Eslab, MTslab, rlb, x, out, b0);
  }
  ln_k<<<4096, 256, 0, stream>>>(out, gamma2, beta2, nb);
  gemm_bt<EPI_GELU><<<dim3(12, 128, 1), 256, 0, stream>>>(nb, w1T, 16384, 768, 192,
      nullptr, hb, b1, nullptr, nullptr, nullptr);
  gemm_bt<EPI_OUT><<<dim3(3, 128, 1), 256, 0, stream>>>(hb, w2T, 16384, 192, 768,
      out, nullptr, b2, nullptr, nullptr, nullptr);
}

// Round 4
// 292.730 us; speedup vs baseline: 1.6975x; 1.3747x over previous
//
#include <hip/hip_runtime.h>
#include <hip/hip_bf16.h>

typedef __hip_bfloat16 bf16;
typedef __attribute__((ext_vector_type(8))) __bf16 bf16x8;
typedef __attribute__((ext_vector_type(4))) float f32x4;

__device__ __forceinline__ void gld_lds16(const bf16* g, bf16* l) {
  __builtin_amdgcn_global_load_lds((const __attribute__((address_space(1))) void*)g,
                                   (__attribute__((address_space(3))) void*)l, 16, 0, 0);
}

// ---------------- weight prep: fp32 -> bf16, transposed / premixed layouts ----------------
__global__ __launch_bounds__(256) void prep_weights(
    const float* __restrict__ wq, const float* __restrict__ wk, const float* __restrict__ wv,
    const float* __restrict__ wo, const float* __restrict__ post_w,
    const float* __restrict__ w1, const float* __restrict__ w2,
    bf16* __restrict__ WqkvT, bf16* __restrict__ W2postT,
    bf16* __restrict__ w1T, bf16* __restrict__ w2T)
{
  int i = blockIdx.x * 256 + threadIdx.x;
  if (i < 331776) {                 // WqkvT[n][d], n: 0..575 q, 576..1151 k, 1152..1727 v
    int n = i / 192, d = i % 192;
    int sel = n / 576, c = n % 576, h = c / 192, kd = c % 192;
    const float* w = (sel == 0) ? wq : (sel == 1 ? wk : wv);
    WqkvT[i] = __float2bfloat16(w[(d*3 + h)*192 + kd]);   // w[D][H][KD]
    return;
  }
  i -= 331776;
  if (i < 331776) {                 // W2postT[n=(h*192+d)][c=(g2*192+kd)] = post_w[h,g2]*wo[c][d]
    int n = i / 576, c = i % 576;
    int h = n / 192, d = n % 192, g2 = c / 192;
    W2postT[i] = __float2bfloat16(post_w[h*3 + g2] * wo[c*192 + d]);
    return;
  }
  i -= 331776;
  if (i < 147456) {                 // w1T[j][d] = w1[d][j], w1 is [192][768]
    int j = i / 192, d = i % 192;
    w1T[i] = __float2bfloat16(w1[d*768 + j]);
    return;
  }
  i -= 147456;
  if (i < 147456) {                 // w2T[d][j] = w2[j][d], w2 is [768][192]
    int d = i / 768, j = i % 768;
    w2T[i] = __float2bfloat16(w2[j*192 + d]);
  }
}

// ---------------- LayerNorm (D=192): 1 wave per row, 4 rows/block ----------------
__global__ __launch_bounds__(256) void ln_k(const float* __restrict__ x,
    const float* __restrict__ gamma, const float* __restrict__ beta,
    bf16* __restrict__ out)
{
  int row = blockIdx.x * 4 + (threadIdx.x >> 6);
  int lane = threadIdx.x & 63;
  const float* xr = x + (size_t)row * 192;
  float v0 = xr[lane], v1 = xr[lane + 64], v2 = xr[lane + 128];
  float s = v0 + v1 + v2;
  #pragma unroll
  for (int o = 32; o; o >>= 1) s += __shfl_xor(s, o);
  float mu = s * (1.f / 192.f);
  float d0 = v0 - mu, d1 = v1 - mu, d2 = v2 - mu;
  float q = d0*d0 + d1*d1 + d2*d2;
  #pragma unroll
  for (int o = 32; o; o >>= 1) q += __shfl_xor(q, o);
  float rs = rsqrtf(q * (1.f / 192.f) + 1e-3f);
  bf16* orow = out + (size_t)row * 192;
  orow[lane]       = __float2bfloat16(d0*rs*gamma[lane]       + beta[lane]);
  orow[lane + 64]  = __float2bfloat16(d1*rs*gamma[lane + 64]  + beta[lane + 64]);
  orow[lane + 128] = __float2bfloat16(d2*rs*gamma[lane + 128] + beta[lane + 128]);
}

// ---------------- generic GEMM C = A[M,K] * BT[N,K]^T, 128x64 tile, 4 waves ----------------
enum { EPI_QKV = 0, EPI_MT = 1, EPI_GELU = 3, EPI_OUT = 4 };

template<int EPI>
__global__ __launch_bounds__(256) void gemm_bt(
    const bf16* __restrict__ A, const bf16* __restrict__ BT,
    int M, int N, int K,
    float* __restrict__ outF, bf16* __restrict__ outB,
    const float* __restrict__ bias,
    bf16* __restrict__ q_out, bf16* __restrict__ k_out, bf16* __restrict__ v_out)
{
  const int tid = threadIdx.x, lane = tid & 63, wid = tid >> 6;
  const int wm = wid >> 1, wn = wid & 1;
  const int row0 = blockIdx.y * 128, col0 = blockIdx.x * 64;
  __shared__ __align__(16) bf16 As[2][128 * 32];
  __shared__ __align__(16) bf16 Bs[2][64 * 32];
  f32x4 acc[4][2] = {};
  const int NT = K >> 5;

#define STAGE(buf_, kt_) do { \
    const bf16* Ab_ = A + (size_t)row0 * K + (kt_) * 32; \
    int c0_ = tid, r0_ = c0_ >> 2, cc0_ = (c0_ & 3) << 3; \
    gld_lds16(Ab_ + (size_t)r0_ * K + cc0_, &As[buf_][c0_ * 8]); \
    int c1_ = tid + 256, r1_ = c1_ >> 2, cc1_ = (c1_ & 3) << 3; \
    gld_lds16(Ab_ + (size_t)r1_ * K + cc1_, &As[buf_][c1_ * 8]); \
    const bf16* Bb_ = BT + (size_t)col0 * K + (kt_) * 32; \
    gld_lds16(Bb_ + (size_t)(tid >> 2) * K + ((tid & 3) << 3), &Bs[buf_][tid * 8]); \
  } while (0)

  STAGE(0, 0);
  for (int kt = 0; kt < NT; ++kt) {
    __syncthreads();
    const int buf = kt & 1;
    if (kt + 1 < NT) STAGE(buf ^ 1, kt + 1);
    const int koff = (lane >> 4) * 8;
    bf16x8 af[4], bfr[2];
    #pragma unroll
    for (int m = 0; m < 4; ++m)
      af[m] = *(const bf16x8*)&As[buf][(wm*64 + m*16 + (lane & 15))*32 + koff];
    #pragma unroll
    for (int n = 0; n < 2; ++n)
      bfr[n] = *(const bf16x8*)&Bs[buf][(wn*32 + n*16 + (lane & 15))*32 + koff];
    #pragma unroll
    for (int m = 0; m < 4; ++m)
      #pragma unroll
      for (int n = 0; n < 2; ++n)
        acc[m][n] = __builtin_amdgcn_mfma_f32_16x16x32_bf16(af[m], bfr[n], acc[m][n], 0, 0, 0);
  }
#undef STAGE

  const int rbase = row0 + wm * 64;
  const int cbase = col0 + wn * 32;
  #pragma unroll
  for (int m = 0; m < 4; ++m) {
    #pragma unroll
    for (int n = 0; n < 2; ++n) {
      const int col = cbase + n*16 + (lane & 15);
      const int rtop = rbase + m*16 + ((lane >> 4) << 2);
      #pragma unroll
      for (int j = 0; j < 4; ++j) {
        const int row = rtop + j;
        const float v = acc[m][n][j];
        if constexpr (EPI == EPI_QKV) {
          const int b = row >> 11, t = row & 2047;
          const int sel = col / 576, c2 = col % 576;
          const bf16 bv = __float2bfloat16(v);
          if (sel == 2) {
            v_out[(size_t)row * 576 + c2] = bv;      // v row-major [b,t,(h,kd)]
          } else {
            const int h = c2 / 192, kd = c2 % 192;
            const size_t hb_ = (size_t)(b * 3 + h);
            if (sel == 0) q_out[(hb_ * 2048 + t) * 192 + kd] = bv;
            else          k_out[(hb_ * 2048 + t) * 192 + kd] = bv;
          }
        } else if constexpr (EPI == EPI_MT) {
          // MT[b][(h*192+d)=col][s=t]
          outB[((size_t)((row >> 11) * 576 + col)) * 2048 + (row & 2047)] = __float2bfloat16(v);
        } else if constexpr (EPI == EPI_GELU) {
          const float u = v + bias[col];
          outB[(size_t)row * 768 + col] =
              __float2bfloat16(0.5f * u * (1.f + erff(u * 0.70710678118654752f)));
        } else if constexpr (EPI == EPI_OUT) {
          const size_t idx = (size_t)row * 192 + col;
          outF[idx] = outF[idx] + v + bias[col];
        }
      }
    }
  }
}

// ---------------- fused attention: out = x + sum_g rl_g * (exp(premixed QK^T/sqrt) * MT_g) ------
// Block: 64 t-rows of one batch. 4 waves. s-loop in steps of 32, no E materialization.
// Wave w: QK rows [w*16, w*16+16); PV d-slice [w*48, w*48+48).
__global__ __launch_bounds__(256, 1) void attn_k(
    const bf16* __restrict__ q, const bf16* __restrict__ k,
    const bf16* __restrict__ MT, const float* __restrict__ pre_w,
    const float* __restrict__ x, float* __restrict__ out)
{
  const int tid = threadIdx.x, lane = tid & 63, w = tid >> 6;
  const int l15 = lane & 15, l4 = lane >> 4;
  const int t0 = blockIdx.x * 64;
  const int b = blockIdx.y;

  // K tiles: [2 buf][h][kq][s(32)][32 elems], 16B slots XOR-swizzled: slot' = slot ^ ((s&3)^((s>>2)&3))
  __shared__ __align__(16) bf16 Ks[2][18432];
  // P tile: [g][t(64)][40] (32 valid + 8 pad) -> conflict-free b128 reads
  __shared__ __align__(16) bf16 Ps[7680];
  __shared__ __align__(16) float rlS[192];

  // Q fragments resident in VGPRs: qf[h][kq]
  bf16x8 qf[3][6];
  #pragma unroll
  for (int h = 0; h < 3; ++h)
    #pragma unroll
    for (int kq = 0; kq < 6; ++kq)
      qf[h][kq] = *(const bf16x8*)(q + ((size_t)(b*3 + h)*2048 + t0 + w*16 + l15)*192 + kq*32 + l4*8);

  float pw[9];
  #pragma unroll
  for (int i = 0; i < 9; ++i) pw[i] = pre_w[i];
  const float rsq = 0.07216878364870323f;  // 1/sqrt(192)

  f32x4 acc[3][4][3] = {};
  float sgacc[3][4] = {};
  const int koff_sw = ((l4 ^ ((l15 & 3) ^ ((l15 >> 2) & 3))) * 8);  // swizzled 16B slot for K reads

#define STAGEK(buf_, s0_) do { \
    _Pragma("unroll") \
    for (int i_ = 0; i_ < 9; ++i_) { \
      const int L_ = i_ * 256 + tid; \
      const int h_ = L_ / 768, r_ = L_ % 768; \
      const int kq_ = r_ >> 7, r2_ = r_ & 127; \
      const int s_ = r2_ >> 2, sl_ = r2_ & 3; \
      const int m_ = (s_ & 3) ^ ((s_ >> 2) & 3); \
      gld_lds16(k + ((size_t)(b*3 + h_)*2048 + (s0_) + s_)*192 + kq_*32 + (sl_ ^ m_)*8, \
                &Ks[buf_][L_ * 8]); \
    } \
  } while (0)

  STAGEK(0, 0);
  for (int st = 0; st < 64; ++st) {
    const int s0 = st * 32;
    const int buf = st & 1;
    __syncthreads();                       // K[buf] staged (vmcnt drained by barrier)

    // MT B-fragments straight from global (L2-hot), issued early to hide latency under QK
    bf16x8 mf[3][3];
    #pragma unroll
    for (int g = 0; g < 3; ++g)
      #pragma unroll
      for (int n = 0; n < 3; ++n)
        mf[g][n] = *(const bf16x8*)(MT + ((size_t)b*576 + g*192 + w*48 + n*16 + l15)*2048 + s0 + l4*8);

    // QK^T: sacc[h][n] over kq
    f32x4 sacc[3][2] = {};
    #pragma unroll
    for (int kq = 0; kq < 6; ++kq)
      #pragma unroll
      for (int h = 0; h < 3; ++h)
        #pragma unroll
        for (int n = 0; n < 2; ++n) {
          const bf16x8 kf = *(const bf16x8*)&Ks[buf][(((h*6 + kq)*32) + n*16 + l15)*32 + koff_sw];
          sacc[h][n] = __builtin_amdgcn_mfma_f32_16x16x32_bf16(qf[h][kq], kf, sacc[h][n], 0, 0, 0);
        }

    // premix + exp + rowsum + P->LDS
    #pragma unroll
    for (int n = 0; n < 2; ++n)
      #pragma unroll
      for (int j = 0; j < 4; ++j) {
        const int tl = w*16 + l4*4 + j;
        const int sl = n*16 + l15;
        #pragma unroll
        for (int g = 0; g < 3; ++g) {
          const float v = (sacc[0][n][j]*pw[g] + sacc[1][n][j]*pw[3+g] + sacc[2][n][j]*pw[6+g]) * rsq;
          const float e = __expf(v);
          sgacc[g][j] += e;
          Ps[g*2560 + tl*40 + sl] = __float2bfloat16(e);
        }
      }
    __syncthreads();                       // P visible

    if (st + 1 < 64) STAGEK(buf ^ 1, s0 + 32);   // overlap staging with PV

    // PV: acc[g][m][n] += P_g[m-frag] x MT_g[n-frag]
    #pragma unroll
    for (int g = 0; g < 3; ++g)
      #pragma unroll
      for (int m = 0; m < 4; ++m) {
        const bf16x8 pf = *(const bf16x8*)&Ps[g*2560 + (m*16 + l15)*40 + l4*8];
        #pragma unroll
        for (int n = 0; n < 3; ++n)
          acc[g][m][n] = __builtin_amdgcn_mfma_f32_16x16x32_bf16(pf, mf[g][n], acc[g][m][n], 0, 0, 0);
      }
  }
#undef STAGEK

  // reduce row sums over the 16-lane group, publish rl = 1/sum
  #pragma unroll
  for (int g = 0; g < 3; ++g)
    #pragma unroll
    for (int j = 0; j < 4; ++j) {
      float s = sgacc[g][j];
      #pragma unroll
      for (int o = 1; o < 16; o <<= 1) s += __shfl_xor(s, o);
      sgacc[g][j] = s;
    }
  __syncthreads();
  if (l15 == 0) {
    #pragma unroll
    for (int g = 0; g < 3; ++g)
      #pragma unroll
      for (int j = 0; j < 4; ++j)
        rlS[g*64 + w*16 + l4*4 + j] = 1.f / sgacc[g][j];
  }
  __syncthreads();

  // epilogue: out = x + sum_g rl_g * acc_g
  #pragma unroll
  for (int m = 0; m < 4; ++m) {
    f32x4 rlf[3];
    #pragma unroll
    for (int g = 0; g < 3; ++g)
      rlf[g] = *(const f32x4*)&rlS[g*64 + m*16 + l4*4];
    #pragma unroll
    for (int n = 0; n < 3; ++n) {
      const int d = w*48 + n*16 + l15;
      #pragma unroll
      for (int j = 0; j < 4; ++j) {
        const int t = t0 + m*16 + l4*4 + j;
        const size_t idx = ((size_t)b*2048 + t)*192 + d;
        out[idx] = x[idx] + rlf[0][j]*acc[0][m][n][j] + rlf[1][j]*acc[1][m][n][j]
                          + rlf[2][j]*acc[2][m][n][j];
      }
    }
  }
}

// ---------------- host launcher ----------------
extern "C" void kernel_launch(void* const* d_in, const int* in_sizes, int n_in,
                              void* d_out, int out_size, void* d_ws, size_t ws_size,
                              hipStream_t stream)
{
  (void)in_sizes; (void)n_in; (void)out_size; (void)ws_size;
  const float* x      = (const float*)d_in[0];
  const float* gamma1 = (const float*)d_in[1];
  const float* beta1  = (const float*)d_in[2];
  const float* gamma2 = (const float*)d_in[3];
  const float* beta2  = (const float*)d_in[4];
  const float* wq     = (const float*)d_in[5];
  const float* wk     = (const float*)d_in[6];
  const float* wv     = (const float*)d_in[7];
  const float* wo     = (const float*)d_in[8];
  const float* pre_w  = (const float*)d_in[9];
  const float* post_w = (const float*)d_in[10];
  const float* w1     = (const float*)d_in[11];
  const float* b1     = (const float*)d_in[12];
  const float* w2     = (const float*)d_in[13];
  const float* b2     = (const float*)d_in[14];
  float* out = (float*)d_out;

  uint8_t* base = (uint8_t*)d_ws;
  size_t off = 0;
  auto alloc = [&](size_t bytes) {
    uint8_t* r = base + off; off += (bytes + 255) & ~(size_t)255; return r;
  };
  bf16* nb      = (bf16*)alloc((size_t)16384 * 192 * 2);    // n1 / n2
  bf16* qb      = (bf16*)alloc((size_t)9437184 * 2);        // q [B,H,T,KD]
  bf16* kb      = (bf16*)alloc((size_t)9437184 * 2);        // k [B,H,T,KD]
  bf16* vb      = (bf16*)alloc((size_t)16384 * 576 * 2);    // v [B,T,(H,KD)]
  bf16* MTslab  = (bf16*)alloc((size_t)8 * 576 * 2048 * 2); // MT [B][(h,d)][s]
  bf16* WqkvT   = (bf16*)alloc((size_t)331776 * 2);
  bf16* W2postT = (bf16*)alloc((size_t)331776 * 2);
  bf16* w1T     = (bf16*)alloc((size_t)147456 * 2);
  bf16* w2T     = (bf16*)alloc((size_t)147456 * 2);
  bf16* hb      = qb;  // overlay: q/k dead by MLP time (25.2MB fits in q+k 37.7MB)

  prep_weights<<<3744, 256, 0, stream>>>(wq, wk, wv, wo, post_w, w1, w2,
                                         WqkvT, W2postT, w1T, w2T);
  ln_k<<<4096, 256, 0, stream>>>(x, gamma1, beta1, nb);
  gemm_bt<EPI_QKV><<<dim3(27, 128, 1), 256, 0, stream>>>(nb, WqkvT, 16384, 1728, 192,
      nullptr, nullptr, nullptr, qb, kb, vb);
  gemm_bt<EPI_MT><<<dim3(9, 128, 1), 256, 0, stream>>>(vb, W2postT, 16384, 576, 576,
      nullptr, MTslab, nullptr, nullptr, nullptr, nullptr);
  attn_k<<<dim3(32, 8), 256, 0, stream>>>(qb, kb, MTslab, pre_w, x, out);
  ln_k<<<4096, 256, 0, stream>>>(out, gamma2, beta2, nb);
  gemm_bt<EPI_GELU><<<dim3(12, 128, 1), 256, 0, stream>>>(nb, w1T, 16384, 768, 192,
      nullptr, hb, b1, nullptr, nullptr, nullptr);
  gemm_bt<EPI_OUT><<<dim3(3, 128, 1), 256, 0, stream>>>(hb, w2T, 16384, 192, 768,
      out, nullptr, b2, nullptr, nullptr, nullptr);
}

// Round 5
// 278.381 us; speedup vs baseline: 1.7850x; 1.0515x over previous
//
#include <hip/hip_runtime.h>
#include <hip/hip_bf16.h>

typedef __hip_bfloat16 bf16;
typedef unsigned char u8;
typedef __attribute__((ext_vector_type(8))) __bf16 bf16x8;
typedef __attribute__((ext_vector_type(4))) float f32x4;

__device__ __forceinline__ void gld_lds16(const void* g, void* l) {
  __builtin_amdgcn_global_load_lds((const __attribute__((address_space(1))) void*)g,
                                   (__attribute__((address_space(3))) void*)l, 16, 0, 0);
}
__device__ __forceinline__ u8 f2e4m3(float v) {
  return (u8)(__builtin_amdgcn_cvt_pk_fp8_f32(v, 0.f, 0, false) & 0xff);
}

// ---------------- weight prep: fp32 -> bf16, transposed / premixed layouts ----------------
__global__ __launch_bounds__(256) void prep_weights(
    const float* __restrict__ wq, const float* __restrict__ wk, const float* __restrict__ wv,
    const float* __restrict__ wo, const float* __restrict__ post_w,
    const float* __restrict__ w1, const float* __restrict__ w2,
    bf16* __restrict__ WqkvT, bf16* __restrict__ W2postT,
    bf16* __restrict__ w1T, bf16* __restrict__ w2T)
{
  int i = blockIdx.x * 256 + threadIdx.x;
  if (i < 331776) {                 // WqkvT[n][d], n: 0..575 q, 576..1151 k, 1152..1727 v
    int n = i / 192, d = i % 192;
    int sel = n / 576, c = n % 576, h = c / 192, kd = c % 192;
    const float* w = (sel == 0) ? wq : (sel == 1 ? wk : wv);
    WqkvT[i] = __float2bfloat16(w[(d*3 + h)*192 + kd]);   // w[D][H][KD]
    return;
  }
  i -= 331776;
  if (i < 331776) {                 // W2postT[n=(h*192+d)][c=(g2*192+kd)] = post_w[h,g2]*wo[c][d]
    int n = i / 576, c = i % 576;
    int h = n / 192, d = n % 192, g2 = c / 192;
    W2postT[i] = __float2bfloat16(post_w[h*3 + g2] * wo[c*192 + d]);
    return;
  }
  i -= 331776;
  if (i < 147456) {                 // w1T[j][d] = w1[d][j], w1 is [192][768]
    int j = i / 192, d = i % 192;
    w1T[i] = __float2bfloat16(w1[d*768 + j]);
    return;
  }
  i -= 147456;
  if (i < 147456) {                 // w2T[d][j] = w2[j][d], w2 is [768][192]
    int d = i / 768, j = i % 768;
    w2T[i] = __float2bfloat16(w2[j*192 + d]);
  }
}

// ---------------- LayerNorm (D=192): 1 wave per row, 4 rows/block ----------------
__global__ __launch_bounds__(256) void ln_k(const float* __restrict__ x,
    const float* __restrict__ gamma, const float* __restrict__ beta,
    bf16* __restrict__ out)
{
  int row = blockIdx.x * 4 + (threadIdx.x >> 6);
  int lane = threadIdx.x & 63;
  const float* xr = x + (size_t)row * 192;
  float v0 = xr[lane], v1 = xr[lane + 64], v2 = xr[lane + 128];
  float s = v0 + v1 + v2;
  #pragma unroll
  for (int o = 32; o; o >>= 1) s += __shfl_xor(s, o);
  float mu = s * (1.f / 192.f);
  float d0 = v0 - mu, d1 = v1 - mu, d2 = v2 - mu;
  float q = d0*d0 + d1*d1 + d2*d2;
  #pragma unroll
  for (int o = 32; o; o >>= 1) q += __shfl_xor(q, o);
  float rs = rsqrtf(q * (1.f / 192.f) + 1e-3f);
  bf16* orow = out + (size_t)row * 192;
  orow[lane]       = __float2bfloat16(d0*rs*gamma[lane]       + beta[lane]);
  orow[lane + 64]  = __float2bfloat16(d1*rs*gamma[lane + 64]  + beta[lane + 64]);
  orow[lane + 128] = __float2bfloat16(d2*rs*gamma[lane + 128] + beta[lane + 128]);
}

// ---------------- generic GEMM C = A[M,K] * BT[N,K]^T, 128x64 tile, 4 waves ----------------
enum { EPI_QKV = 0, EPI_MT = 1, EPI_GELU = 3, EPI_OUT = 4 };

template<int EPI>
__global__ __launch_bounds__(256) void gemm_bt(
    const bf16* __restrict__ A, const bf16* __restrict__ BT,
    int M, int N, int K,
    float* __restrict__ outF, bf16* __restrict__ outB,
    const float* __restrict__ bias,
    u8* __restrict__ q_out, u8* __restrict__ k_out, bf16* __restrict__ v_out,
    u8* __restrict__ mt_out)
{
  const int tid = threadIdx.x, lane = tid & 63, wid = tid >> 6;
  const int wm = wid >> 1, wn = wid & 1;
  const int row0 = blockIdx.y * 128, col0 = blockIdx.x * 64;
  __shared__ __align__(16) bf16 As[2][128 * 32];
  __shared__ __align__(16) bf16 Bs[2][64 * 32];
  f32x4 acc[4][2] = {};
  const int NT = K >> 5;

#define STAGE(buf_, kt_) do { \
    const bf16* Ab_ = A + (size_t)row0 * K + (kt_) * 32; \
    int c0_ = tid, r0_ = c0_ >> 2, cc0_ = (c0_ & 3) << 3; \
    gld_lds16(Ab_ + (size_t)r0_ * K + cc0_, &As[buf_][c0_ * 8]); \
    int c1_ = tid + 256, r1_ = c1_ >> 2, cc1_ = (c1_ & 3) << 3; \
    gld_lds16(Ab_ + (size_t)r1_ * K + cc1_, &As[buf_][c1_ * 8]); \
    const bf16* Bb_ = BT + (size_t)col0 * K + (kt_) * 32; \
    gld_lds16(Bb_ + (size_t)(tid >> 2) * K + ((tid & 3) << 3), &Bs[buf_][tid * 8]); \
  } while (0)

  STAGE(0, 0);
  for (int kt = 0; kt < NT; ++kt) {
    __syncthreads();
    const int buf = kt & 1;
    if (kt + 1 < NT) STAGE(buf ^ 1, kt + 1);
    const int koff = (lane >> 4) * 8;
    bf16x8 af[4], bfr[2];
    #pragma unroll
    for (int m = 0; m < 4; ++m)
      af[m] = *(const bf16x8*)&As[buf][(wm*64 + m*16 + (lane & 15))*32 + koff];
    #pragma unroll
    for (int n = 0; n < 2; ++n)
      bfr[n] = *(const bf16x8*)&Bs[buf][(wn*32 + n*16 + (lane & 15))*32 + koff];
    #pragma unroll
    for (int m = 0; m < 4; ++m)
      #pragma unroll
      for (int n = 0; n < 2; ++n)
        acc[m][n] = __builtin_amdgcn_mfma_f32_16x16x32_bf16(af[m], bfr[n], acc[m][n], 0, 0, 0);
  }
#undef STAGE

  const int rbase = row0 + wm * 64;
  const int cbase = col0 + wn * 32;
  #pragma unroll
  for (int m = 0; m < 4; ++m) {
    #pragma unroll
    for (int n = 0; n < 2; ++n) {
      const int col = cbase + n*16 + (lane & 15);
      const int rtop = rbase + m*16 + ((lane >> 4) << 2);
      if constexpr (EPI == EPI_MT) {
        // MT[b][(h*192+d)=col][s], 4 consecutive s -> packed fp8 dword
        int pk = __builtin_amdgcn_cvt_pk_fp8_f32(acc[m][n][0], acc[m][n][1], 0, false);
        pk = __builtin_amdgcn_cvt_pk_fp8_f32(acc[m][n][2], acc[m][n][3], pk, true);
        *(unsigned*)&mt_out[((size_t)((rtop >> 11) * 576 + col)) * 2048 + (rtop & 2047)] = (unsigned)pk;
      } else {
        #pragma unroll
        for (int j = 0; j < 4; ++j) {
          const int row = rtop + j;
          const float v = acc[m][n][j];
          if constexpr (EPI == EPI_QKV) {
            const int b = row >> 11, t = row & 2047;
            const int sel = col / 576, c2 = col % 576;
            if (sel == 2) {
              v_out[(size_t)row * 576 + c2] = __float2bfloat16(v);  // v row-major [b,t,(h,kd)]
            } else {
              const int h = c2 / 192, kd = c2 % 192;
              const size_t hb_ = (size_t)(b * 3 + h);
              if (sel == 0) q_out[(hb_ * 2048 + t) * 192 + kd] = f2e4m3(v);
              else          k_out[(hb_ * 2048 + t) * 192 + kd] = f2e4m3(v);
            }
          } else if constexpr (EPI == EPI_GELU) {
            const float u = v + bias[col];
            outB[(size_t)row * 768 + col] =
                __float2bfloat16(0.5f * u * (1.f + erff(u * 0.70710678118654752f)));
          } else if constexpr (EPI == EPI_OUT) {
            const size_t idx = (size_t)row * 192 + col;
            outF[idx] = outF[idx] + v + bias[col];
          }
        }
      }
    }
  }
}

// ---------------- fused attention (fp8 core): out = x + sum_g rl_g * (exp(premix QK^T/sqrt) * MT_g)
// Block: 32 t-rows of one batch, 4 waves, 2 blocks/CU. s-loop in steps of 32.
// QK: wave (tq=w&1, sq=w>>1): rows tq*16, s-half sq*16. PV: wave w owns d-slice w*48, both m.
__global__ __launch_bounds__(256, 2) void attn_k(
    const u8* __restrict__ q, const u8* __restrict__ k,
    const u8* __restrict__ MT, const float* __restrict__ pre_w,
    const float* __restrict__ x, float* __restrict__ out)
{
  const int tid = threadIdx.x, lane = tid & 63, w = tid >> 6;
  const int l15 = lane & 15, l4 = lane >> 4;
  const int tq = w & 1, sq = w >> 1;
  const int t0 = blockIdx.x * 32;
  const int b = blockIdx.y;

  // K tile: [2 buf][(h*6+kq)*32+s rows][32 fp8], 16B halves swapped by (s>>3)&1
  __shared__ __align__(16) u8 Ks[2][18432];
  // P tile: [g][t(32)][40] fp8 (32 valid + 8 pad)
  __shared__ __align__(16) u8 Ps[3840];
  __shared__ float rlPart[2][3][32];

  // Q fragments resident: qf[h][kq] (8 fp8 each)
  long qf[3][6];
  #pragma unroll
  for (int h = 0; h < 3; ++h)
    #pragma unroll
    for (int kq = 0; kq < 6; ++kq)
      qf[h][kq] = *(const long*)(q + ((size_t)(b*3 + h)*2048 + t0 + tq*16 + l15)*192 + kq*32 + l4*8);

  float pw[9];
  #pragma unroll
  for (int i = 0; i < 9; ++i) pw[i] = pre_w[i];
  const float rsq = 0.07216878364870323f;  // 1/sqrt(192)

  f32x4 acc[3][2][3] = {};
  float sgacc[3][4] = {};
  const int krow = sq*16 + l15;
  const int kslot = (l4 ^ (((krow >> 3) & 1) << 1)) * 8;

#define STAGEK(buf_, s0_) do { \
    _Pragma("unroll") \
    for (int i_ = 0; i_ < 5; ++i_) { \
      const int L_ = i_ * 256 + tid; \
      if (L_ < 1152) { \
        const int h_ = L_ / 384, r_ = L_ - h_*384; \
        const int kq_ = r_ >> 6, r2_ = r_ & 63; \
        const int s_ = r2_ >> 1, half_ = r2_ & 1; \
        const int hs_ = (s_ >> 3) & 1; \
        gld_lds16(k + ((size_t)(b*3 + h_)*2048 + (s0_) + s_)*192 + kq_*32 + (half_ ^ hs_)*16, \
                  &Ks[buf_][L_ * 16]); \
      } \
    } \
  } while (0)

  STAGEK(0, 0);
  for (int st = 0; st < 64; ++st) {
    const int s0 = st * 32;
    const int buf = st & 1;
    __syncthreads();                       // K[buf] ready; Ps free to overwrite

    // MT B-fragments from global (L2-hot), issued early; wave w: d-slice w*48
    long mf[3][3];
    #pragma unroll
    for (int g = 0; g < 3; ++g)
      #pragma unroll
      for (int n = 0; n < 3; ++n)
        mf[g][n] = *(const long*)(MT + ((size_t)b*576 + g*192 + w*48 + n*16 + l15)*2048 + s0 + l4*8);

    // QK^T: 16 t-rows x 16 s-cols per wave
    f32x4 sacc[3] = {};
    #pragma unroll
    for (int kq = 0; kq < 6; ++kq)
      #pragma unroll
      for (int h = 0; h < 3; ++h) {
        const long kf = *(const long*)&Ks[buf][(((h*6 + kq)*32) + krow)*32 + kslot];
        sacc[h] = __builtin_amdgcn_mfma_f32_16x16x32_fp8_fp8(qf[h][kq], kf, sacc[h], 0, 0, 0);
      }

    // premix + exp + rowsum partial + P->LDS (fp8, packed pairs over j)
    float eg[3][4];
    #pragma unroll
    for (int j = 0; j < 4; ++j)
      #pragma unroll
      for (int g = 0; g < 3; ++g) {
        const float v = (sacc[0][j]*pw[g] + sacc[1][j]*pw[3+g] + sacc[2][j]*pw[6+g]) * rsq;
        const float e = __expf(v);
        eg[g][j] = e;
        sgacc[g][j] += e;
      }
    {
      const int tlb = tq*16 + l4*4;
      const int sl = sq*16 + l15;
      #pragma unroll
      for (int g = 0; g < 3; ++g) {
        const int pk01 = __builtin_amdgcn_cvt_pk_fp8_f32(eg[g][0], eg[g][1], 0, false);
        const int pk23 = __builtin_amdgcn_cvt_pk_fp8_f32(eg[g][2], eg[g][3], 0, false);
        Ps[g*1280 + (tlb+0)*40 + sl] = (u8)pk01;
        Ps[g*1280 + (tlb+1)*40 + sl] = (u8)(pk01 >> 8);
        Ps[g*1280 + (tlb+2)*40 + sl] = (u8)pk23;
        Ps[g*1280 + (tlb+3)*40 + sl] = (u8)(pk23 >> 8);
      }
    }
    __syncthreads();                       // P visible; K[buf] reads done

    if (st + 1 < 64) STAGEK(buf ^ 1, s0 + 32);   // overlap staging with PV

    // PV: acc[g][m][n] += P_g[m-frag] x MT_g[n-frag]
    #pragma unroll
    for (int g = 0; g < 3; ++g)
      #pragma unroll
      for (int m = 0; m < 2; ++m) {
        const long pf = *(const long*)&Ps[g*1280 + (m*16 + l15)*40 + l4*8];
        #pragma unroll
        for (int n = 0; n < 3; ++n)
          acc[g][m][n] = __builtin_amdgcn_mfma_f32_16x16x32_fp8_fp8(pf, mf[g][n], acc[g][m][n], 0, 0, 0);
      }
  }
#undef STAGEK

  // reduce row-sum partials over the 16-lane group, publish per s-half
  #pragma unroll
  for (int g = 0; g < 3; ++g)
    #pragma unroll
    for (int j = 0; j < 4; ++j) {
      float s = sgacc[g][j];
      #pragma unroll
      for (int o = 1; o < 16; o <<= 1) s += __shfl_xor(s, o);
      sgacc[g][j] = s;
    }
  __syncthreads();
  if (l15 == 0) {
    #pragma unroll
    for (int g = 0; g < 3; ++g)
      #pragma unroll
      for (int j = 0; j < 4; ++j)
        rlPart[sq][g][tq*16 + l4*4 + j] = sgacc[g][j];
  }
  __syncthreads();

  // epilogue: out = x + sum_g rl_g * acc_g   (wave w: d-slice w*48, both m)
  #pragma unroll
  for (int m = 0; m < 2; ++m) {
    #pragma unroll
    for (int j = 0; j < 4; ++j) {
      const int row = m*16 + l4*4 + j;
      float rlv[3];
      #pragma unroll
      for (int g = 0; g < 3; ++g)
        rlv[g] = 1.f / (rlPart[0][g][row] + rlPart[1][g][row]);
      #pragma unroll
      for (int n = 0; n < 3; ++n) {
        const int d = w*48 + n*16 + l15;
        const size_t idx = ((size_t)b*2048 + t0 + row)*192 + d;
        out[idx] = x[idx] + rlv[0]*acc[0][m][n][j] + rlv[1]*acc[1][m][n][j]
                          + rlv[2]*acc[2][m][n][j];
      }
    }
  }
}

// ---------------- host launcher ----------------
extern "C" void kernel_launch(void* const* d_in, const int* in_sizes, int n_in,
                              void* d_out, int out_size, void* d_ws, size_t ws_size,
                              hipStream_t stream)
{
  (void)in_sizes; (void)n_in; (void)out_size; (void)ws_size;
  const float* x      = (const float*)d_in[0];
  const float* gamma1 = (const float*)d_in[1];
  const float* beta1  = (const float*)d_in[2];
  const float* gamma2 = (const float*)d_in[3];
  const float* beta2  = (const float*)d_in[4];
  const float* wq     = (const float*)d_in[5];
  const float* wk     = (const float*)d_in[6];
  const float* wv     = (const float*)d_in[7];
  const float* wo     = (const float*)d_in[8];
  const float* pre_w  = (const float*)d_in[9];
  const float* post_w = (const float*)d_in[10];
  const float* w1     = (const float*)d_in[11];
  const float* b1     = (const float*)d_in[12];
  const float* w2     = (const float*)d_in[13];
  const float* b2     = (const float*)d_in[14];
  float* out = (float*)d_out;

  uint8_t* base = (uint8_t*)d_ws;
  size_t off = 0;
  auto alloc = [&](size_t bytes) {
    uint8_t* r = base + off; off += (bytes + 255) & ~(size_t)255; return r;
  };
  bf16* nb      = (bf16*)alloc((size_t)16384 * 192 * 2);    // n1 / n2
  u8*   qb      = (u8*)alloc((size_t)9437184);              // q fp8 [B,H,T,KD]
  u8*   kb      = (u8*)alloc((size_t)9437184);              // k fp8 [B,H,T,KD]
  bf16* vb      = (bf16*)alloc((size_t)16384 * 576 * 2);    // v bf16 [B,T,(H,KD)]
  u8*   MTslab  = (u8*)alloc((size_t)8 * 576 * 2048);       // MT fp8 [B][(h,d)][s]
  bf16* WqkvT   = (bf16*)alloc((size_t)331776 * 2);
  bf16* W2postT = (bf16*)alloc((size_t)331776 * 2);
  bf16* w1T     = (bf16*)alloc((size_t)147456 * 2);
  bf16* w2T     = (bf16*)alloc((size_t)147456 * 2);
  bf16* hb      = (bf16*)qb;  // overlay: q/k/v dead by MLP time (25.2MB fits in q+k+v ~37.7MB)

  prep_weights<<<3744, 256, 0, stream>>>(wq, wk, wv, wo, post_w, w1, w2,
                                         WqkvT, W2postT, w1T, w2T);
  ln_k<<<4096, 256, 0, stream>>>(x, gamma1, beta1, nb);
  gemm_bt<EPI_QKV><<<dim3(27, 128, 1), 256, 0, stream>>>(nb, WqkvT, 16384, 1728, 192,
      nullptr, nullptr, nullptr, qb, kb, vb, nullptr);
  gemm_bt<EPI_MT><<<dim3(9, 128, 1), 256, 0, stream>>>(vb, W2postT, 16384, 576, 576,
      nullptr, nullptr, nullptr, nullptr, nullptr, nullptr, MTslab);
  attn_k<<<dim3(64, 8), 256, 0, stream>>>(qb, kb, MTslab, pre_w, x, out);
  ln_k<<<4096, 256, 0, stream>>>(out, gamma2, beta2, nb);
  gemm_bt<EPI_GELU><<<dim3(12, 128, 1), 256, 0, stream>>>(nb, w1T, 16384, 768, 192,
      nullptr, hb, b1, nullptr, nullptr, nullptr, nullptr);
  gemm_bt<EPI_OUT><<<dim3(3, 128, 1), 256, 0, stream>>>(hb, w2T, 16384, 192, 768,
      out, nullptr, b2, nullptr, nullptr, nullptr, nullptr);
}